// Round 13
// baseline (137.465 us; speedup 1.0000x reference)
//
#include <hip/hip_runtime.h>
#include <math.h>

#define OVERLAP_THRESH 0.35f
#define VALID_THRESH   0.2f
#define NEGPOS         7
#define TMAX           64
#define NCHUNK         16   // prior chunks per (b,t) argmax
#define TPW            4    // targets per wave in best_prior
#define EPT            4    // priors per thread in fused match+loss
#define HB             2048 // 11-bit coarse histogram buckets (u >> 20, sign bit 0)
#define NC             4    // LDS hist copies (contention spread)
#define NSCAN          32   // blocks per batch in topk_scan

__device__ __forceinline__ float sl1(float x) {
    float ax = fabsf(x);
    return ax < 1.0f ? 0.5f * ax * ax : ax - 0.5f;
}
__device__ __forceinline__ float frcp(float x) { return __builtin_amdgcn_rcpf(x); }

__device__ __forceinline__ void atomicMaxU8(unsigned char* addr, unsigned char val) {
    size_t a = (size_t)addr;
    unsigned* word = (unsigned*)(a & ~(size_t)3);
    int shift = (int)(a & 3) * 8;
    unsigned old = *word, assumed;
    do {
        unsigned cur = (old >> shift) & 0xFFu;
        if (cur >= val) break;
        assumed = old;
        unsigned nw = (old & ~(0xFFu << shift)) | ((unsigned)val << shift);
        old = atomicCAS(word, assumed, nw);
    } while (old != assumed);
}

// ---------------- K0: fast workspace clear ------------------------------------------
__global__ void clear_ws_kernel(uint4* __restrict__ p, size_t n16) {
    size_t i = (size_t)blockIdx.x * blockDim.x + threadIdx.x;
    size_t stride = (size_t)gridDim.x * blockDim.x;
    uint4 z = make_uint4(0u, 0u, 0u, 0u);
    for (; i < n16; i += stride) p[i] = z;
}

// ---- single-wave coarse-bucket select from ghist[b]: d1 (bucket), r (rank in bucket)
__device__ __forceinline__ void select_coarse(const int* gh, int K, int lane,
                                              int* s_d1, int* s_r) {
    int base = lane * 32;
    int v[32]; int s = 0;
    #pragma unroll
    for (int j = 0; j < 32; j++) { v[j] = gh[base + j]; s += v[j]; }
    int sfx = s;
    for (int off = 1; off < 64; off <<= 1) {
        int t = __shfl_down(sfx, off);
        if (lane + off < 64) sfx += t;
    }
    int ge = sfx;
    #pragma unroll
    for (int j = 0; j < 32; j++) {
        int gen = ge - v[j];
        if (ge >= K && gen < K) { *s_d1 = base + j; *s_r = K - gen; }
        ge = gen;
    }
}

// ---------------- K2: partial best-prior, split-K over priors, 4 targets/wave --------
__global__ void best_prior_partial_kernel(const float* __restrict__ priors,
                                          const float* __restrict__ targets,
                                          int P, int BT,
                                          unsigned long long* __restrict__ keys) {
    int wid  = blockIdx.x * (blockDim.x >> 6) + (threadIdx.x >> 6);
    int lane = threadIdx.x & 63;
    int ng    = (BT + TPW - 1) / TPW;
    int group = wid % ng;
    int chunk = wid / ng;
    int bt0   = group * TPW;

    float tx1[TPW], ty1[TPW], tx2[TPW], ty2[TPW], ta[TPW];
    #pragma unroll
    for (int j = 0; j < TPW; j++) {
        int bt = min(bt0 + j, BT - 1);
        const float* tg = targets + (size_t)bt * 15;
        tx1[j] = tg[0]; ty1[j] = tg[1]; tx2[j] = tg[2]; ty2[j] = tg[3];
        ta[j]  = (tx2[j] - tx1[j]) * (ty2[j] - ty1[j]);
    }

    int cs = (P + NCHUNK - 1) / NCHUNK;
    int p0 = chunk * cs;
    int pend = min(p0 + cs, P);
    float best[TPW]; int bestp[TPW];
    #pragma unroll
    for (int j = 0; j < TPW; j++) { best[j] = -1.0f; bestp[j] = p0; }

    for (int p = p0 + lane; p < pend; p += 64) {
        float4 pr = ((const float4*)priors)[p];
        float hw = pr.z * 0.5f, hh = pr.w * 0.5f;
        float px1 = pr.x - hw, py1 = pr.y - hh;
        float px2 = pr.x + hw, py2 = pr.y + hh;
        float pa = (px2 - px1) * (py2 - py1);
        #pragma unroll
        for (int j = 0; j < TPW; j++) {
            float iw = fmaxf(fminf(tx2[j], px2) - fmaxf(tx1[j], px1), 0.0f);
            float ih = fmaxf(fminf(ty2[j], py2) - fmaxf(ty1[j], py1), 0.0f);
            float inter = iw * ih;
            float iou = inter * frcp(ta[j] + pa - inter);
            if (iou > best[j]) { best[j] = iou; bestp[j] = p; }  // strict >: lowest p/lane
        }
    }
    #pragma unroll
    for (int j = 0; j < TPW; j++) {
        unsigned long long key =
            ((unsigned long long)__float_as_uint(fmaxf(best[j], 0.0f)) << 32) |
            (unsigned long long)(0xFFFFFFFFu - (unsigned)bestp[j]);
        for (int off = 32; off; off >>= 1) {
            unsigned long long k2 = __shfl_down(key, off);
            if (k2 > key) key = k2;
        }
        if (lane == 0 && bt0 + j < BT) atomicMax(&keys[bt0 + j], key);
    }
}

// ---------------- K2b: unpack keys -> u8 override map / valid bitmask / any_valid ----
__global__ void unpack_override_kernel(const unsigned long long* __restrict__ keys,
                                       int T, int BT, int P,
                                       unsigned char* __restrict__ ovr8,
                                       unsigned* __restrict__ vmask,
                                       int* __restrict__ av_arr) {
    int i = blockIdx.x * blockDim.x + threadIdx.x;
    if (i >= BT) return;
    unsigned long long k = keys[i];
    int bpi = (int)(0xFFFFFFFFu - (unsigned)(k & 0xFFFFFFFFull));
    float iou = __uint_as_float((unsigned)(k >> 32));
    int b = i / T, t = i % T;
    atomicMaxU8(&ovr8[(size_t)b * P + bpi], (unsigned char)(t + 1)); // last write wins == largest t
    if (iou >= VALID_THRESH) {
        atomicOr(&vmask[(size_t)b * (P >> 5) + (bpi >> 5)], 1u << (bpi & 31));
        atomicOr(&av_arr[b], 1);
    }
}

// ---------------- K3: FUSED match (t-loop argmax) + loss eval, EPT priors/thread -----
__global__ void match_loss_fused_kernel(const float* __restrict__ priors,
                                        const float* __restrict__ targets,
                                        const float* __restrict__ loc_data,
                                        const float* __restrict__ conf_data,
                                        const float* __restrict__ landm_data,
                                        const unsigned char* __restrict__ ovr8,
                                        const unsigned* __restrict__ vmask,
                                        const int* __restrict__ av_arr,
                                        int P, int T,
                                        float* __restrict__ rank_loss,
                                        int* __restrict__ ghist,      // [B][HB]
                                        int* __restrict__ num_pos,    // [B]
                                        int* __restrict__ num_pos1,   // [B]
                                        float* __restrict__ accb)     // [B][3]
{
    int b   = blockIdx.y;
    int tid = threadIdx.x;
    int p0  = (blockIdx.x * blockDim.x + tid) * EPT;
    size_t base = (size_t)b * P + p0;

    __shared__ float4 s_box[TMAX];
    __shared__ float  s_ba[TMAX];
    __shared__ float  s_lab[TMAX];
    __shared__ int    s_hist[HB][NC];
    __shared__ float  s_ll, s_llm, s_cep;
    __shared__ int    s_np, s_np1;

    if (tid == 0) { s_ll = 0.f; s_llm = 0.f; s_cep = 0.f; s_np = 0; s_np1 = 0; }
    for (int i = tid; i < HB; i += blockDim.x)
        *(int4*)&s_hist[i][0] = make_int4(0, 0, 0, 0);
    if (tid < T) {
        const float* tg = targets + ((size_t)b * T + tid) * 15;
        float x1 = tg[0], y1 = tg[1], x2 = tg[2], y2 = tg[3];
        s_box[tid] = make_float4(x1, y1, x2, y2);
        s_ba[tid]  = (x2 - x1) * (y2 - y1);
        s_lab[tid] = tg[14];
    }
    __syncthreads();

    int hc = tid & (NC - 1);
    int av = av_arr[b];
    float ll_s = 0.f, cep_s = 0.f, llm_s = 0.f;
    int np_s = 0, np1_s = 0;

    if (p0 + EPT <= P) {
        // prior geometry (loaded once, reused for IoU and encode)
        float px1[EPT], py1[EPT], px2[EPT], py2[EPT], pa[EPT];
        float pcx[EPT], pcy[EPT], pw[EPT], ph[EPT];
        float best[EPT]; int btidx[EPT];
        #pragma unroll
        for (int j = 0; j < EPT; j++) {
            float4 pr = ((const float4*)priors)[p0 + j];
            float hw = pr.z * 0.5f, hh = pr.w * 0.5f;
            px1[j] = pr.x - hw; py1[j] = pr.y - hh;
            px2[j] = pr.x + hw; py2[j] = pr.y + hh;
            pa[j]  = pr.z * pr.w * 0.0f + (px2[j] - px1[j]) * (py2[j] - py1[j]);
            pcx[j] = pr.x; pcy[j] = pr.y; pw[j] = pr.z; ph[j] = pr.w;
            best[j] = -1.0f; btidx[j] = 0;
        }

        // t-loop argmax: 1 broadcast ds_read_b128 + ds_read per t
        #pragma unroll 8
        for (int t = 0; t < TMAX; t++) {
            float4 box = s_box[t];
            float  ba  = s_ba[t];
            #pragma unroll
            for (int j = 0; j < EPT; j++) {
                float iw = fmaxf(fminf(box.z, px2[j]) - fmaxf(box.x, px1[j]), 0.0f);
                float ih = fmaxf(fminf(box.w, py2[j]) - fmaxf(box.y, py1[j]), 0.0f);
                float inter = iw * ih;
                float iou = inter * frcp(ba + pa[j] - inter);
                if (iou > best[j]) { best[j] = iou; btidx[j] = t; }   // first occurrence
            }
        }

        // overrides + loss eval
        unsigned ov4 = *(const unsigned*)&ovr8[base];
        unsigned vb  = vmask[(size_t)b * (P >> 5) + (p0 >> 5)] >> (p0 & 31);
        float cc[2 * EPT];
        *(float4*)&cc[0] = ((const float4*)(conf_data + base * 2))[0];
        *(float4*)&cc[4] = ((const float4*)(conf_data + base * 2))[1];

        float rl[EPT]; int btv[EPT]; float cev[EPT]; int posv[EPT];
        #pragma unroll
        for (int j = 0; j < EPT; j++) {
            int bt = btidx[j];
            int ov = (ov4 >> (8 * j)) & 0xFF;
            if (ov) bt = ov - 1;
            float bv = best[j];
            if ((vb >> j) & 1u) bv = 2.0f;
            btv[j] = bt;

            bool cond = (av && bv >= OVERLAP_THRESH);
            float lab = cond ? s_lab[bt] : 0.0f;
            int   ci  = (int)lab;
            bool  pos = cond && (ci != 0);
            posv[j] = pos;

            float c0 = cc[2 * j], c1 = cc[2 * j + 1];
            float mx = fmaxf(c0, c1);
            float lse = mx + __logf(1.0f + __expf(-fabsf(c0 - c1)));
            float ce  = lse - (pos ? c1 : c0);
            cev[j] = ce;
            rl[j] = pos ? 0.0f : fmaxf(ce, 0.0f);
            atomicAdd(&s_hist[__float_as_uint(rl[j]) >> 20][hc], 1);
        }
        *(float4*)&rank_loss[base] = *(float4*)rl;

        #pragma unroll
        for (int j = 0; j < EPT; j++) {
            if (!posv[j]) continue;
            int bt = btv[j];
            size_t idx = base + j;
            float4 mb = s_box[bt];
            bool pos1 = ((int)s_lab[bt] > 0);

            float rx = frcp(0.1f * pw[j]), ry = frcp(0.1f * ph[j]);
            float gx = ((mb.x + mb.z) * 0.5f - pcx[j]) * rx;
            float gy = ((mb.y + mb.w) * 0.5f - pcy[j]) * ry;
            float gw = __logf((mb.z - mb.x) * frcp(pw[j])) * 5.0f;
            float gh = __logf((mb.w - mb.y) * frcp(ph[j])) * 5.0f;
            const float* ld = loc_data + idx * 4;
            ll_s += sl1(ld[0] - gx) + sl1(ld[1] - gy) + sl1(ld[2] - gw) + sl1(ld[3] - gh);
            cep_s += cev[j];
            np_s++;

            if (pos1) {
                const float* lmd = landm_data + idx * 10;
                const float* lm  = targets + ((size_t)b * T + bt) * 15 + 4;
                float s = 0.0f;
                #pragma unroll
                for (int k = 0; k < 5; k++) {
                    float gxl = (lm[2 * k]     - pcx[j]) * rx;
                    float gyl = (lm[2 * k + 1] - pcy[j]) * ry;
                    s += sl1(lmd[2 * k] - gxl) + sl1(lmd[2 * k + 1] - gyl);
                }
                llm_s += s;
                np1_s++;
            }
        }
    }

    if (np_s)  { atomicAdd(&s_ll, ll_s); atomicAdd(&s_cep, cep_s); atomicAdd(&s_np, np_s); }
    if (np1_s) { atomicAdd(&s_llm, llm_s); atomicAdd(&s_np1, np1_s); }
    __syncthreads();
    if (tid == 0) {
        if (s_np)  { atomicAdd(&num_pos[b], s_np);
                     atomicAdd(&accb[b * 3 + 0], s_ll);
                     atomicAdd(&accb[b * 3 + 2], s_cep); }
        if (s_np1) { atomicAdd(&num_pos1[b], s_np1);
                     atomicAdd(&accb[b * 3 + 1], s_llm); }
    }
    for (int i = tid; i < HB; i += blockDim.x) {
        int4 v4 = *(int4*)&s_hist[i][0];
        int v = v4.x + v4.y + v4.z + v4.w;
        if (v) atomicAdd(&ghist[(size_t)b * HB + i], v);
    }
}

// ---- single-wave digit select over nb (<=256) buckets in LDS hist ----
__device__ __forceinline__ void select_digit(const int* hist, int nb, int tid,
                                             int* s_dig, int* s_r) {
    if (tid < 64) {
        int lane = tid;
        int per  = (nb >= 64) ? (nb >> 6) : 1;
        int base = lane * per;
        int v[4]; int s = 0;
        #pragma unroll
        for (int j = 0; j < 4; j++) {
            int idx = base + j;
            int h = (j < per && idx < nb) ? hist[idx] : 0;
            v[j] = h; s += h;
        }
        int sfx = s;
        for (int off = 1; off < 64; off <<= 1) {
            int t = __shfl_down(sfx, off);
            if (lane + off < 64) sfx += t;
        }
        int r  = *s_r;
        int ge = sfx;
        #pragma unroll
        for (int j = 0; j < 4; j++) {
            int gen = ge - v[j];
            int d   = base + j;
            if (j < per && d < nb && ge >= r && gen < r) { *s_dig = d; *s_r = r - gen; }
            ge = gen;
        }
    }
}

// ---------------- K4a: parallel scan — S_hi/C_hi + compact boundary bucket -----------
__global__ void topk_scan_kernel(const float* __restrict__ rank_loss,
                                 const int* __restrict__ num_pos,
                                 const int* __restrict__ ghist,
                                 int P,
                                 float* __restrict__ glist,   // [B][P]
                                 int* __restrict__ gcnt,      // [B]
                                 float* __restrict__ accS,    // [B]
                                 int* __restrict__ accC) {    // [B]
    int b    = blockIdx.y;
    int tid  = threadIdx.x;
    int lane = tid & 63;
    int wv   = tid >> 6;
    long long Kll = (long long)num_pos[b] * NEGPOS;
    int K = (Kll > P - 1) ? (P - 1) : (int)Kll;
    if (K <= 0) return;

    __shared__ int   s_d1, s_rdummy;
    __shared__ int   s_lcnt, s_base;
    __shared__ float s_stage[1024];
    __shared__ float s_S[4];
    __shared__ int   s_C[4];

    if (tid == 0) s_lcnt = 0;
    if (wv == 0) select_coarse(ghist + (size_t)b * HB, K, lane, &s_d1, &s_rdummy);
    __syncthreads();
    int d1 = s_d1;
    unsigned hi_lim = ((unsigned)(d1 + 1)) << 20;

    const float4* v4 = (const float4*)(rank_loss + (size_t)b * P);
    int n4  = P >> 2;
    int per = (n4 + NSCAN - 1) / NSCAN;
    int i0  = blockIdx.x * per;
    int i1  = min(i0 + per, n4);

    float S = 0.f; int C = 0;
    for (int i = i0 + tid; i < i1; i += blockDim.x) {
        float4 x = v4[i];
        float xs[4] = {x.x, x.y, x.z, x.w};
        #pragma unroll
        for (int k = 0; k < 4; k++) {
            unsigned u = __float_as_uint(xs[k]);
            if (u >= hi_lim) { S += xs[k]; C++; }
            bool m = ((u >> 20) == (unsigned)d1);
            unsigned long long mk = __ballot(m);
            if (m) {
                int leader = __ffsll((long long)mk) - 1;
                int base = 0;
                if (lane == leader) base = atomicAdd(&s_lcnt, __popcll(mk));  // LDS-local
                base = __shfl(base, leader);
                int ofs = __popcll(mk & (((unsigned long long)1 << lane) - 1ull));
                s_stage[base + ofs] = xs[k];
            }
        }
    }
    for (int off = 32; off; off >>= 1) {
        S += __shfl_down(S, off);
        C += __shfl_down(C, off);
    }
    if (lane == 0) { s_S[wv] = S; s_C[wv] = C; }
    __syncthreads();
    if (tid == 0) {
        float St = 0.f; int Ct = 0;
        for (int i = 0; i < 4; i++) { St += s_S[i]; Ct += s_C[i]; }
        if (Ct) { atomicAdd(&accS[b], St); atomicAdd(&accC[b], Ct); }
        s_base = s_lcnt ? atomicAdd(&gcnt[b], s_lcnt) : 0;   // ONE reservation per block
    }
    __syncthreads();
    int lc = s_lcnt, gbase = s_base;
    float* gl = glist + (size_t)b * P;
    for (int i = tid; i < lc; i += blockDim.x) gl[gbase + i] = s_stage[i];  // coalesced
}

// ---------------- K4b: refine + FUSED finalize (last-block pattern) ------------------
__global__ void topk_refine_finalize_kernel(const int* __restrict__ num_pos,
                                            const int* __restrict__ num_pos1,
                                            const float* __restrict__ accb,
                                            const int* __restrict__ ghist,
                                            int P, int B,
                                            const float* __restrict__ glist,
                                            const int* __restrict__ gcnt,
                                            const float* __restrict__ accS,
                                            const int* __restrict__ accC,
                                            float* __restrict__ accn,   // [B]
                                            int* __restrict__ done_ctr, // [1]
                                            float* __restrict__ out) {
    int b    = blockIdx.x;
    int tid  = threadIdx.x;
    int lane = tid & 63;
    int wv   = tid >> 6;
    long long Kll = (long long)num_pos[b] * NEGPOS;
    int K = (Kll > P - 1) ? (P - 1) : (int)Kll;

    __shared__ int   hist[256];
    __shared__ int   s_d1, s_r, s_dig;
    __shared__ float s_S[16];
    __shared__ int   s_C[16];
    __shared__ float s_res;

    if (tid == 0) s_res = 0.0f;
    __syncthreads();

    if (K > 0) {
        if (wv == 0) select_coarse(ghist + (size_t)b * HB, K, lane, &s_d1, &s_r);
        __syncthreads();
        int d1 = s_d1;
        int lc = gcnt[b];
        const float* gl = glist + (size_t)b * P;

        unsigned pmask = 0u, pval = 0u;
        const int shf[3] = {12, 4, 0};
        const int nbk[3] = {256, 256, 16};
        for (int ps = 0; ps < 3; ps++) {
            int sh = shf[ps]; unsigned wm = (unsigned)(nbk[ps] - 1);
            if (tid < 256) hist[tid] = 0;
            __syncthreads();
            for (int i = tid; i < lc; i += blockDim.x) {
                unsigned u = __float_as_uint(gl[i]);
                if ((u & pmask) == pval) atomicAdd(&hist[(u >> sh) & wm], 1);
            }
            __syncthreads();
            select_digit(hist, nbk[ps], tid, &s_dig, &s_r);
            __syncthreads();
            pval  |= ((unsigned)s_dig) << sh;
            pmask |= wm << sh;
        }
        float tau = __uint_as_float((((unsigned)d1) << 20) | pval);

        float S = 0.f; int C = 0;
        for (int i = tid; i < lc; i += blockDim.x) {
            float x = gl[i];
            if (x > tau) { S += x; C++; }
        }
        for (int off = 32; off; off >>= 1) {
            S += __shfl_down(S, off);
            C += __shfl_down(C, off);
        }
        if (lane == 0) { s_S[wv] = S; s_C[wv] = C; }
        __syncthreads();
        if (tid == 0) {
            float St = accS[b]; int Ct = accC[b];
            int nw = blockDim.x >> 6;
            for (int i = 0; i < nw; i++) { St += s_S[i]; Ct += s_C[i]; }
            s_res = St + (float)(K - Ct) * tau;
        }
        __syncthreads();
    }

    // last-block finalize (device-scope: atomic read-back of accn)
    if (tid == 0) {
        accn[b] = s_res;
        __threadfence();
        if (atomicAdd(done_ctr, 1) == B - 1) {
            float cen = 0.f;
            for (int j = 0; j < B; j++) cen += atomicAdd(&accn[j], 0.0f);  // coherent read
            int tp = 0, tp1 = 0;
            float ll = 0.f, llm = 0.f, cep = 0.f;
            for (int j = 0; j < B; j++) {
                tp  += num_pos[j];
                tp1 += num_pos1[j];
                ll  += accb[j * 3 + 0];
                llm += accb[j * 3 + 1];
                cep += accb[j * 3 + 2];
            }
            float N  = fmaxf((float)tp, 1.0f);
            float N1 = fmaxf((float)tp1, 1.0f);
            out[0] = ll / N;
            out[1] = (cep + cen) / N;
            out[2] = llm / N1;
        }
    }
}

extern "C" void kernel_launch(void* const* d_in, const int* in_sizes, int n_in,
                              void* d_out, int out_size, void* d_ws, size_t ws_size,
                              hipStream_t stream) {
    const float* loc_data   = (const float*)d_in[0];
    const float* conf_data  = (const float*)d_in[1];
    const float* landm_data = (const float*)d_in[2];
    const float* priors     = (const float*)d_in[3];
    const float* targets    = (const float*)d_in[4];
    float* out = (float*)d_out;

    int P  = in_sizes[3] / 4;
    int BP = in_sizes[0] / 4;
    int B  = BP / P;
    int T  = in_sizes[4] / (B * 15);
    int BT = B * T;

    char* ws = (char*)d_ws;
    float* rank_loss = (float*)ws;                    size_t off = (size_t)B * P * sizeof(float);
    float* glist     = (float*)(ws + off);            off += (size_t)B * P * sizeof(float);
    // zeroed region starts here (16B-aligned)
    unsigned char* ovr8 = (unsigned char*)(ws + off); off += (size_t)B * P;
    unsigned* vmask = (unsigned*)(ws + off); off += (size_t)B * (P >> 5) * sizeof(unsigned);
    int* ghist      = (int*)(ws + off);      off += (size_t)B * HB * sizeof(int);
    unsigned long long* keys = (unsigned long long*)(ws + off); off += (size_t)BT * sizeof(unsigned long long);
    int* av_arr     = (int*)(ws + off);      off += (size_t)B * sizeof(int);
    int* num_pos    = (int*)(ws + off);      off += (size_t)B * sizeof(int);
    int* num_pos1   = (int*)(ws + off);      off += (size_t)B * sizeof(int);
    float* accb     = (float*)(ws + off);    off += (size_t)B * 3 * sizeof(float);
    float* accn     = (float*)(ws + off);    off += (size_t)B * sizeof(float);
    int* gcnt       = (int*)(ws + off);      off += (size_t)B * sizeof(int);
    float* accS     = (float*)(ws + off);    off += (size_t)B * sizeof(float);
    int* accC       = (int*)(ws + off);      off += (size_t)B * sizeof(int);
    int* done_ctr   = (int*)(ws + off);      off += sizeof(int);

    // K0: clear zeroed region
    size_t zbytes = (size_t)((char*)(done_ctr + 1) - (char*)ovr8);
    size_t n16 = (zbytes + 15) / 16;
    clear_ws_kernel<<<256, 256, 0, stream>>>((uint4*)ovr8, n16);

    // K2: split-K best-prior, 4 targets per wave.
    int waves   = NCHUNK * ((BT + TPW - 1) / TPW);
    int blocks2 = (waves + 3) / 4;
    best_prior_partial_kernel<<<blocks2, 256, 0, stream>>>(priors, targets, P, BT, keys);

    // K2b: unpack scatter-override map (u8 CAS-max).
    unpack_override_kernel<<<(BT + 255) / 256, 256, 0, stream>>>(keys, T, BT, P,
                                                                 ovr8, vmask, av_arr);

    // K3: fused match (argmax over truths) + loss eval + coarse histogram.
    dim3 gm((P + 256 * EPT - 1) / (256 * EPT), B);
    match_loss_fused_kernel<<<gm, 256, 0, stream>>>(priors, targets, loc_data, conf_data,
                                                    landm_data, ovr8, vmask, av_arr, P, T,
                                                    rank_loss, ghist, num_pos, num_pos1, accb);

    // K4a: parallel top-K scan (512 blocks, block-local staging).
    dim3 gs(NSCAN, B);
    topk_scan_kernel<<<gs, 256, 0, stream>>>(rank_loss, num_pos, ghist, P,
                                             glist, gcnt, accS, accC);

    // K4b: refine boundary bucket + last-block finalize.
    topk_refine_finalize_kernel<<<B, 1024, 0, stream>>>(num_pos, num_pos1, accb, ghist,
                                                        P, B, glist, gcnt, accS, accC,
                                                        accn, done_ctr, out);
}

// Round 14
// 104.518 us; speedup vs baseline: 1.3152x; 1.3152x over previous
//
#include <hip/hip_runtime.h>
#include <math.h>

#define OVERLAP_THRESH 0.35f
#define VALID_THRESH   0.2f
#define NEGPOS         7
#define TMAX           64
#define NCHUNK         16   // prior chunks per (b,t) argmax
#define TPW            4    // targets per wave in best_prior
#define EPT            4    // priors per thread in fused match+loss
#define HB             2048 // 11-bit coarse histogram buckets (u >> 20, sign bit 0)
#define NC             4    // LDS hist copies (contention spread)
#define NSCAN          32   // blocks per batch in topk_scan

__device__ __forceinline__ float sl1(float x) {
    float ax = fabsf(x);
    return ax < 1.0f ? 0.5f * ax * ax : ax - 0.5f;
}
__device__ __forceinline__ float frcp(float x) { return __builtin_amdgcn_rcpf(x); }

__device__ __forceinline__ void atomicMaxU8(unsigned char* addr, unsigned char val) {
    size_t a = (size_t)addr;
    unsigned* word = (unsigned*)(a & ~(size_t)3);
    int shift = (int)(a & 3) * 8;
    unsigned old = *word, assumed;
    do {
        unsigned cur = (old >> shift) & 0xFFu;
        if (cur >= val) break;
        assumed = old;
        unsigned nw = (old & ~(0xFFu << shift)) | ((unsigned)val << shift);
        old = atomicCAS(word, assumed, nw);
    } while (old != assumed);
}

// ---------------- K0: fast workspace clear ------------------------------------------
__global__ void clear_ws_kernel(uint4* __restrict__ p, size_t n16) {
    size_t i = (size_t)blockIdx.x * blockDim.x + threadIdx.x;
    size_t stride = (size_t)gridDim.x * blockDim.x;
    uint4 z = make_uint4(0u, 0u, 0u, 0u);
    for (; i < n16; i += stride) p[i] = z;
}

// ---- single-wave coarse-bucket select from ghist[b]: d1 (bucket), r (rank in bucket)
__device__ __forceinline__ void select_coarse(const int* gh, int K, int lane,
                                              int* s_d1, int* s_r) {
    int base = lane * 32;
    int v[32]; int s = 0;
    #pragma unroll
    for (int j = 0; j < 32; j++) { v[j] = gh[base + j]; s += v[j]; }
    int sfx = s;
    for (int off = 1; off < 64; off <<= 1) {
        int t = __shfl_down(sfx, off);
        if (lane + off < 64) sfx += t;
    }
    int ge = sfx;
    #pragma unroll
    for (int j = 0; j < 32; j++) {
        int gen = ge - v[j];
        if (ge >= K && gen < K) { *s_d1 = base + j; *s_r = K - gen; }
        ge = gen;
    }
}

// ---------------- K2: partial best-prior, split-K over priors, 4 targets/wave --------
__global__ void best_prior_partial_kernel(const float* __restrict__ priors,
                                          const float* __restrict__ targets,
                                          int P, int BT,
                                          unsigned long long* __restrict__ keys) {
    int wid  = blockIdx.x * (blockDim.x >> 6) + (threadIdx.x >> 6);
    int lane = threadIdx.x & 63;
    int ng    = (BT + TPW - 1) / TPW;
    int group = wid % ng;
    int chunk = wid / ng;
    int bt0   = group * TPW;

    float tx1[TPW], ty1[TPW], tx2[TPW], ty2[TPW], ta[TPW];
    #pragma unroll
    for (int j = 0; j < TPW; j++) {
        int bt = min(bt0 + j, BT - 1);
        const float* tg = targets + (size_t)bt * 15;
        tx1[j] = tg[0]; ty1[j] = tg[1]; tx2[j] = tg[2]; ty2[j] = tg[3];
        ta[j]  = (tx2[j] - tx1[j]) * (ty2[j] - ty1[j]);
    }

    int cs = (P + NCHUNK - 1) / NCHUNK;
    int p0 = chunk * cs;
    int pend = min(p0 + cs, P);
    float best[TPW]; int bestp[TPW];
    #pragma unroll
    for (int j = 0; j < TPW; j++) { best[j] = -1.0f; bestp[j] = p0; }

    for (int p = p0 + lane; p < pend; p += 64) {
        float4 pr = ((const float4*)priors)[p];
        float hw = pr.z * 0.5f, hh = pr.w * 0.5f;
        float px1 = pr.x - hw, py1 = pr.y - hh;
        float px2 = pr.x + hw, py2 = pr.y + hh;
        float pa = (px2 - px1) * (py2 - py1);
        #pragma unroll
        for (int j = 0; j < TPW; j++) {
            float iw = fmaxf(fminf(tx2[j], px2) - fmaxf(tx1[j], px1), 0.0f);
            float ih = fmaxf(fminf(ty2[j], py2) - fmaxf(ty1[j], py1), 0.0f);
            float inter = iw * ih;
            float iou = inter * frcp(ta[j] + pa - inter);
            if (iou > best[j]) { best[j] = iou; bestp[j] = p; }  // strict >: lowest p/lane
        }
    }
    #pragma unroll
    for (int j = 0; j < TPW; j++) {
        unsigned long long key =
            ((unsigned long long)__float_as_uint(fmaxf(best[j], 0.0f)) << 32) |
            (unsigned long long)(0xFFFFFFFFu - (unsigned)bestp[j]);
        for (int off = 32; off; off >>= 1) {
            unsigned long long k2 = __shfl_down(key, off);
            if (k2 > key) key = k2;
        }
        if (lane == 0 && bt0 + j < BT) atomicMax(&keys[bt0 + j], key);
    }
}

// ---------------- K2b: unpack keys -> u8 override map / valid bitmask / any_valid ----
__global__ void unpack_override_kernel(const unsigned long long* __restrict__ keys,
                                       int T, int BT, int P,
                                       unsigned char* __restrict__ ovr8,
                                       unsigned* __restrict__ vmask,
                                       int* __restrict__ av_arr) {
    int i = blockIdx.x * blockDim.x + threadIdx.x;
    if (i >= BT) return;
    unsigned long long k = keys[i];
    int bpi = (int)(0xFFFFFFFFu - (unsigned)(k & 0xFFFFFFFFull));
    float iou = __uint_as_float((unsigned)(k >> 32));
    int b = i / T, t = i % T;
    atomicMaxU8(&ovr8[(size_t)b * P + bpi], (unsigned char)(t + 1)); // last write wins == largest t
    if (iou >= VALID_THRESH) {
        atomicOr(&vmask[(size_t)b * (P >> 5) + (bpi >> 5)], 1u << (bpi & 31));
        atomicOr(&av_arr[b], 1);
    }
}

// ---------------- K3: FUSED match (t-loop argmax) + loss eval, EPT priors/thread -----
__global__ void match_loss_fused_kernel(const float* __restrict__ priors,
                                        const float* __restrict__ targets,
                                        const float* __restrict__ loc_data,
                                        const float* __restrict__ conf_data,
                                        const float* __restrict__ landm_data,
                                        const unsigned char* __restrict__ ovr8,
                                        const unsigned* __restrict__ vmask,
                                        const int* __restrict__ av_arr,
                                        int P, int T,
                                        float* __restrict__ rank_loss,
                                        int* __restrict__ ghist,      // [B][HB]
                                        int* __restrict__ num_pos,    // [B]
                                        int* __restrict__ num_pos1,   // [B]
                                        float* __restrict__ accb)     // [B][3]
{
    int b   = blockIdx.y;
    int tid = threadIdx.x;
    int p0  = (blockIdx.x * blockDim.x + tid) * EPT;
    size_t base = (size_t)b * P + p0;

    __shared__ float4 s_box[TMAX];
    __shared__ float  s_ba[TMAX];
    __shared__ float  s_lab[TMAX];
    __shared__ int    s_hist[HB][NC];
    __shared__ float  s_ll, s_llm, s_cep;
    __shared__ int    s_np, s_np1;

    if (tid == 0) { s_ll = 0.f; s_llm = 0.f; s_cep = 0.f; s_np = 0; s_np1 = 0; }
    for (int i = tid; i < HB; i += blockDim.x)
        *(int4*)&s_hist[i][0] = make_int4(0, 0, 0, 0);
    if (tid < T) {
        const float* tg = targets + ((size_t)b * T + tid) * 15;
        float x1 = tg[0], y1 = tg[1], x2 = tg[2], y2 = tg[3];
        s_box[tid] = make_float4(x1, y1, x2, y2);
        s_ba[tid]  = (x2 - x1) * (y2 - y1);
        s_lab[tid] = tg[14];
    }
    __syncthreads();

    int hc = tid & (NC - 1);
    int av = av_arr[b];
    float ll_s = 0.f, cep_s = 0.f, llm_s = 0.f;
    int np_s = 0, np1_s = 0;

    if (p0 + EPT <= P) {
        float px1[EPT], py1[EPT], px2[EPT], py2[EPT], pa[EPT];
        float pcx[EPT], pcy[EPT], pw[EPT], ph[EPT];
        float best[EPT]; int btidx[EPT];
        #pragma unroll
        for (int j = 0; j < EPT; j++) {
            float4 pr = ((const float4*)priors)[p0 + j];
            float hw = pr.z * 0.5f, hh = pr.w * 0.5f;
            px1[j] = pr.x - hw; py1[j] = pr.y - hh;
            px2[j] = pr.x + hw; py2[j] = pr.y + hh;
            pa[j]  = (px2[j] - px1[j]) * (py2[j] - py1[j]);
            pcx[j] = pr.x; pcy[j] = pr.y; pw[j] = pr.z; ph[j] = pr.w;
            best[j] = -1.0f; btidx[j] = 0;
        }

        #pragma unroll 8
        for (int t = 0; t < TMAX; t++) {
            float4 box = s_box[t];
            float  ba  = s_ba[t];
            #pragma unroll
            for (int j = 0; j < EPT; j++) {
                float iw = fmaxf(fminf(box.z, px2[j]) - fmaxf(box.x, px1[j]), 0.0f);
                float ih = fmaxf(fminf(box.w, py2[j]) - fmaxf(box.y, py1[j]), 0.0f);
                float inter = iw * ih;
                float iou = inter * frcp(ba + pa[j] - inter);
                if (iou > best[j]) { best[j] = iou; btidx[j] = t; }   // first occurrence
            }
        }

        unsigned ov4 = *(const unsigned*)&ovr8[base];
        unsigned vb  = vmask[(size_t)b * (P >> 5) + (p0 >> 5)] >> (p0 & 31);
        float cc[2 * EPT];
        *(float4*)&cc[0] = ((const float4*)(conf_data + base * 2))[0];
        *(float4*)&cc[4] = ((const float4*)(conf_data + base * 2))[1];

        float rl[EPT]; int btv[EPT]; float cev[EPT]; int posv[EPT];
        #pragma unroll
        for (int j = 0; j < EPT; j++) {
            int bt = btidx[j];
            int ov = (ov4 >> (8 * j)) & 0xFF;
            if (ov) bt = ov - 1;
            float bv = best[j];
            if ((vb >> j) & 1u) bv = 2.0f;
            btv[j] = bt;

            bool cond = (av && bv >= OVERLAP_THRESH);
            float lab = cond ? s_lab[bt] : 0.0f;
            int   ci  = (int)lab;
            bool  pos = cond && (ci != 0);
            posv[j] = pos;

            float c0 = cc[2 * j], c1 = cc[2 * j + 1];
            float mx = fmaxf(c0, c1);
            float lse = mx + __logf(1.0f + __expf(-fabsf(c0 - c1)));
            float ce  = lse - (pos ? c1 : c0);
            cev[j] = ce;
            rl[j] = pos ? 0.0f : fmaxf(ce, 0.0f);
            atomicAdd(&s_hist[__float_as_uint(rl[j]) >> 20][hc], 1);
        }
        *(float4*)&rank_loss[base] = *(float4*)rl;

        #pragma unroll
        for (int j = 0; j < EPT; j++) {
            if (!posv[j]) continue;
            int bt = btv[j];
            size_t idx = base + j;
            float4 mb = s_box[bt];
            bool pos1 = ((int)s_lab[bt] > 0);

            float rx = frcp(0.1f * pw[j]), ry = frcp(0.1f * ph[j]);
            float gx = ((mb.x + mb.z) * 0.5f - pcx[j]) * rx;
            float gy = ((mb.y + mb.w) * 0.5f - pcy[j]) * ry;
            float gw = __logf((mb.z - mb.x) * frcp(pw[j])) * 5.0f;
            float gh = __logf((mb.w - mb.y) * frcp(ph[j])) * 5.0f;
            const float* ld = loc_data + idx * 4;
            ll_s += sl1(ld[0] - gx) + sl1(ld[1] - gy) + sl1(ld[2] - gw) + sl1(ld[3] - gh);
            cep_s += cev[j];
            np_s++;

            if (pos1) {
                const float* lmd = landm_data + idx * 10;
                const float* lm  = targets + ((size_t)b * T + bt) * 15 + 4;
                float s = 0.0f;
                #pragma unroll
                for (int k = 0; k < 5; k++) {
                    float gxl = (lm[2 * k]     - pcx[j]) * rx;
                    float gyl = (lm[2 * k + 1] - pcy[j]) * ry;
                    s += sl1(lmd[2 * k] - gxl) + sl1(lmd[2 * k + 1] - gyl);
                }
                llm_s += s;
                np1_s++;
            }
        }
    }

    if (np_s)  { atomicAdd(&s_ll, ll_s); atomicAdd(&s_cep, cep_s); atomicAdd(&s_np, np_s); }
    if (np1_s) { atomicAdd(&s_llm, llm_s); atomicAdd(&s_np1, np1_s); }
    __syncthreads();
    if (tid == 0) {
        if (s_np)  { atomicAdd(&num_pos[b], s_np);
                     atomicAdd(&accb[b * 3 + 0], s_ll);
                     atomicAdd(&accb[b * 3 + 2], s_cep); }
        if (s_np1) { atomicAdd(&num_pos1[b], s_np1);
                     atomicAdd(&accb[b * 3 + 1], s_llm); }
    }
    for (int i = tid; i < HB; i += blockDim.x) {
        int4 v4 = *(int4*)&s_hist[i][0];
        int v = v4.x + v4.y + v4.z + v4.w;
        if (v) atomicAdd(&ghist[(size_t)b * HB + i], v);
    }
}

// ---- single-wave digit select over nb (<=256) buckets in LDS hist ----
__device__ __forceinline__ void select_digit(const int* hist, int nb, int tid,
                                             int* s_dig, int* s_r) {
    if (tid < 64) {
        int lane = tid;
        int per  = (nb >= 64) ? (nb >> 6) : 1;
        int base = lane * per;
        int v[4]; int s = 0;
        #pragma unroll
        for (int j = 0; j < 4; j++) {
            int idx = base + j;
            int h = (j < per && idx < nb) ? hist[idx] : 0;
            v[j] = h; s += h;
        }
        int sfx = s;
        for (int off = 1; off < 64; off <<= 1) {
            int t = __shfl_down(sfx, off);
            if (lane + off < 64) sfx += t;
        }
        int r  = *s_r;
        int ge = sfx;
        #pragma unroll
        for (int j = 0; j < 4; j++) {
            int gen = ge - v[j];
            int d   = base + j;
            if (j < per && d < nb && ge >= r && gen < r) { *s_dig = d; *s_r = r - gen; }
            ge = gen;
        }
    }
}

// ---------------- K4a: parallel scan — S_hi/C_hi + compact boundary bucket -----------
// d1 == 0 (zeros bucket, the common case when K is clamped): skip compaction —
// tau = 0 exactly, bucket contributes nothing.
__global__ void topk_scan_kernel(const float* __restrict__ rank_loss,
                                 const int* __restrict__ num_pos,
                                 const int* __restrict__ ghist,
                                 int P,
                                 float* __restrict__ glist,   // [B][P]
                                 int* __restrict__ gcnt,      // [B]
                                 float* __restrict__ accS,    // [B]
                                 int* __restrict__ accC) {    // [B]
    int b    = blockIdx.y;
    int tid  = threadIdx.x;
    int lane = tid & 63;
    int wv   = tid >> 6;
    long long Kll = (long long)num_pos[b] * NEGPOS;
    int K = (Kll > P - 1) ? (P - 1) : (int)Kll;
    if (K <= 0) return;

    __shared__ int   s_d1, s_rdummy;
    __shared__ int   s_lcnt, s_base;
    __shared__ float s_stage[1024];
    __shared__ float s_S[4];
    __shared__ int   s_C[4];

    if (tid == 0) s_lcnt = 0;
    if (wv == 0) select_coarse(ghist + (size_t)b * HB, K, lane, &s_d1, &s_rdummy);
    __syncthreads();
    int d1 = s_d1;
    unsigned hi_lim = ((unsigned)(d1 + 1)) << 20;

    const float4* v4 = (const float4*)(rank_loss + (size_t)b * P);
    int n4  = P >> 2;
    int per = (n4 + NSCAN - 1) / NSCAN;
    int i0  = blockIdx.x * per;
    int i1  = min(i0 + per, n4);

    float S = 0.f; int C = 0;
    if (d1 == 0) {
        // zeros bucket: no compaction needed (tau = 0)
        for (int i = i0 + tid; i < i1; i += blockDim.x) {
            float4 x = v4[i];
            float xs[4] = {x.x, x.y, x.z, x.w};
            #pragma unroll
            for (int k = 0; k < 4; k++) {
                unsigned u = __float_as_uint(xs[k]);
                if (u >= hi_lim) { S += xs[k]; C++; }
            }
        }
    } else {
        for (int i = i0 + tid; i < i1; i += blockDim.x) {
            float4 x = v4[i];
            float xs[4] = {x.x, x.y, x.z, x.w};
            #pragma unroll
            for (int k = 0; k < 4; k++) {
                unsigned u = __float_as_uint(xs[k]);
                if (u >= hi_lim) { S += xs[k]; C++; }
                bool m = ((u >> 20) == (unsigned)d1);
                unsigned long long mk = __ballot(m);
                if (m) {
                    int leader = __ffsll((long long)mk) - 1;
                    int base = 0;
                    if (lane == leader) base = atomicAdd(&s_lcnt, __popcll(mk));  // LDS-local
                    base = __shfl(base, leader);
                    int ofs = __popcll(mk & (((unsigned long long)1 << lane) - 1ull));
                    s_stage[base + ofs] = xs[k];
                }
            }
        }
    }
    for (int off = 32; off; off >>= 1) {
        S += __shfl_down(S, off);
        C += __shfl_down(C, off);
    }
    if (lane == 0) { s_S[wv] = S; s_C[wv] = C; }
    __syncthreads();
    if (tid == 0) {
        float St = 0.f; int Ct = 0;
        for (int i = 0; i < 4; i++) { St += s_S[i]; Ct += s_C[i]; }
        if (Ct) { atomicAdd(&accS[b], St); atomicAdd(&accC[b], Ct); }
        s_base = s_lcnt ? atomicAdd(&gcnt[b], s_lcnt) : 0;   // ONE reservation per block
    }
    __syncthreads();
    int lc = s_lcnt, gbase = s_base;
    float* gl = glist + (size_t)b * P;
    for (int i = tid; i < lc; i += blockDim.x) gl[gbase + i] = s_stage[i];
}

// ---------------- K4b: refine + FUSED finalize (last-block pattern) ------------------
// d1 == 0 shortcut: tau = 0, result = accS. Generic path: ballot-aggregated hist
// (1 atomic per same-digit group per wave -> immune to identical-value concentration).
__global__ void topk_refine_finalize_kernel(const int* __restrict__ num_pos,
                                            const int* __restrict__ num_pos1,
                                            const float* __restrict__ accb,
                                            const int* __restrict__ ghist,
                                            int P, int B,
                                            const float* __restrict__ glist,
                                            const int* __restrict__ gcnt,
                                            const float* __restrict__ accS,
                                            const int* __restrict__ accC,
                                            float* __restrict__ accn,   // [B]
                                            int* __restrict__ done_ctr, // [1]
                                            float* __restrict__ out) {
    int b    = blockIdx.x;
    int tid  = threadIdx.x;
    int lane = tid & 63;
    int wv   = tid >> 6;
    long long Kll = (long long)num_pos[b] * NEGPOS;
    int K = (Kll > P - 1) ? (P - 1) : (int)Kll;

    __shared__ int   hist[256];
    __shared__ int   s_d1, s_r, s_dig;
    __shared__ float s_S[16];
    __shared__ int   s_C[16];
    __shared__ float s_res;

    if (tid == 0) s_res = 0.0f;
    __syncthreads();

    if (K > 0) {
        if (wv == 0) select_coarse(ghist + (size_t)b * HB, K, lane, &s_d1, &s_r);
        __syncthreads();
        int d1 = s_d1;

        if (d1 == 0) {
            // tau = 0 exactly: top-K sum = sum of all values above bucket 0
            if (tid == 0) s_res = accS[b];
            __syncthreads();
        } else {
            int lc = gcnt[b];
            const float* gl = glist + (size_t)b * P;

            unsigned pmask = 0u, pval = 0u;
            const int shf[3] = {12, 4, 0};
            const int nbk[3] = {256, 256, 16};
            int trips = (lc + blockDim.x - 1) / blockDim.x;
            for (int ps = 0; ps < 3; ps++) {
                int sh = shf[ps]; unsigned wm = (unsigned)(nbk[ps] - 1);
                if (tid < 256) hist[tid] = 0;
                __syncthreads();
                for (int tc = 0; tc < trips; tc++) {
                    int i = tc * blockDim.x + tid;
                    bool ok = (i < lc);
                    unsigned u = ok ? __float_as_uint(gl[i]) : 0u;
                    ok = ok && ((u & pmask) == pval);
                    unsigned d = (u >> sh) & wm;
                    // ballot-aggregate: 1 LDS atomic per same-digit group per wave
                    unsigned long long m = __ballot(ok);
                    #pragma unroll
                    for (int bit = 0; bit < 8; bit++) {
                        unsigned long long bb = __ballot((d >> bit) & 1u);
                        m &= ((d >> bit) & 1u) ? bb : ~bb;
                    }
                    if (ok && lane == (__ffsll((long long)m) - 1))
                        atomicAdd(&hist[d], __popcll(m));
                }
                __syncthreads();
                select_digit(hist, nbk[ps], tid, &s_dig, &s_r);
                __syncthreads();
                pval  |= ((unsigned)s_dig) << sh;
                pmask |= wm << sh;
            }
            float tau = __uint_as_float((((unsigned)d1) << 20) | pval);

            float S = 0.f; int C = 0;
            for (int i = tid; i < lc; i += blockDim.x) {
                float x = gl[i];
                if (x > tau) { S += x; C++; }
            }
            for (int off = 32; off; off >>= 1) {
                S += __shfl_down(S, off);
                C += __shfl_down(C, off);
            }
            if (lane == 0) { s_S[wv] = S; s_C[wv] = C; }
            __syncthreads();
            if (tid == 0) {
                float St = accS[b]; int Ct = accC[b];
                int nw = blockDim.x >> 6;
                for (int i = 0; i < nw; i++) { St += s_S[i]; Ct += s_C[i]; }
                s_res = St + (float)(K - Ct) * tau;
            }
            __syncthreads();
        }
    }

    // last-block finalize (device-scope: atomic read-back of accn)
    if (tid == 0) {
        accn[b] = s_res;
        __threadfence();
        if (atomicAdd(done_ctr, 1) == B - 1) {
            float cen = 0.f;
            for (int j = 0; j < B; j++) cen += atomicAdd(&accn[j], 0.0f);  // coherent read
            int tp = 0, tp1 = 0;
            float ll = 0.f, llm = 0.f, cep = 0.f;
            for (int j = 0; j < B; j++) {
                tp  += num_pos[j];
                tp1 += num_pos1[j];
                ll  += accb[j * 3 + 0];
                llm += accb[j * 3 + 1];
                cep += accb[j * 3 + 2];
            }
            float N  = fmaxf((float)tp, 1.0f);
            float N1 = fmaxf((float)tp1, 1.0f);
            out[0] = ll / N;
            out[1] = (cep + cen) / N;
            out[2] = llm / N1;
        }
    }
}

extern "C" void kernel_launch(void* const* d_in, const int* in_sizes, int n_in,
                              void* d_out, int out_size, void* d_ws, size_t ws_size,
                              hipStream_t stream) {
    const float* loc_data   = (const float*)d_in[0];
    const float* conf_data  = (const float*)d_in[1];
    const float* landm_data = (const float*)d_in[2];
    const float* priors     = (const float*)d_in[3];
    const float* targets    = (const float*)d_in[4];
    float* out = (float*)d_out;

    int P  = in_sizes[3] / 4;
    int BP = in_sizes[0] / 4;
    int B  = BP / P;
    int T  = in_sizes[4] / (B * 15);
    int BT = B * T;

    char* ws = (char*)d_ws;
    float* rank_loss = (float*)ws;                    size_t off = (size_t)B * P * sizeof(float);
    float* glist     = (float*)(ws + off);            off += (size_t)B * P * sizeof(float);
    // zeroed region starts here (16B-aligned)
    unsigned char* ovr8 = (unsigned char*)(ws + off); off += (size_t)B * P;
    unsigned* vmask = (unsigned*)(ws + off); off += (size_t)B * (P >> 5) * sizeof(unsigned);
    int* ghist      = (int*)(ws + off);      off += (size_t)B * HB * sizeof(int);
    unsigned long long* keys = (unsigned long long*)(ws + off); off += (size_t)BT * sizeof(unsigned long long);
    int* av_arr     = (int*)(ws + off);      off += (size_t)B * sizeof(int);
    int* num_pos    = (int*)(ws + off);      off += (size_t)B * sizeof(int);
    int* num_pos1   = (int*)(ws + off);      off += (size_t)B * sizeof(int);
    float* accb     = (float*)(ws + off);    off += (size_t)B * 3 * sizeof(float);
    float* accn     = (float*)(ws + off);    off += (size_t)B * sizeof(float);
    int* gcnt       = (int*)(ws + off);      off += (size_t)B * sizeof(int);
    float* accS     = (float*)(ws + off);    off += (size_t)B * sizeof(float);
    int* accC       = (int*)(ws + off);      off += (size_t)B * sizeof(int);
    int* done_ctr   = (int*)(ws + off);      off += sizeof(int);

    // K0: clear zeroed region
    size_t zbytes = (size_t)((char*)(done_ctr + 1) - (char*)ovr8);
    size_t n16 = (zbytes + 15) / 16;
    clear_ws_kernel<<<256, 256, 0, stream>>>((uint4*)ovr8, n16);

    // K2: split-K best-prior, 4 targets per wave.
    int waves   = NCHUNK * ((BT + TPW - 1) / TPW);
    int blocks2 = (waves + 3) / 4;
    best_prior_partial_kernel<<<blocks2, 256, 0, stream>>>(priors, targets, P, BT, keys);

    // K2b: unpack scatter-override map (u8 CAS-max).
    unpack_override_kernel<<<(BT + 255) / 256, 256, 0, stream>>>(keys, T, BT, P,
                                                                 ovr8, vmask, av_arr);

    // K3: fused match (argmax over truths) + loss eval + coarse histogram.
    dim3 gm((P + 256 * EPT - 1) / (256 * EPT), B);
    match_loss_fused_kernel<<<gm, 256, 0, stream>>>(priors, targets, loc_data, conf_data,
                                                    landm_data, ovr8, vmask, av_arr, P, T,
                                                    rank_loss, ghist, num_pos, num_pos1, accb);

    // K4a: parallel top-K scan (512 blocks, block-local staging).
    dim3 gs(NSCAN, B);
    topk_scan_kernel<<<gs, 256, 0, stream>>>(rank_loss, num_pos, ghist, P,
                                             glist, gcnt, accS, accC);

    // K4b: refine boundary bucket + last-block finalize.
    topk_refine_finalize_kernel<<<B, 1024, 0, stream>>>(num_pos, num_pos1, accb, ghist,
                                                        P, B, glist, gcnt, accS, accC,
                                                        accn, done_ctr, out);
}